// Round 2
// baseline (3393.967 us; speedup 1.0000x reference)
//
#include <hip/hip_runtime.h>

#define EPS 1e-5f

// ---------------- workspace layout (float offsets) ----------------
constexpr size_t F_U3 = 0;                               // (16,64, 8, 8)
constexpr size_t F_U2 = F_U3 + (size_t)16*64*64;         // (16,64,16,16)
constexpr size_t F_U1 = F_U2 + (size_t)16*64*256;        // (16,64,32,32)
constexpr size_t F_S3 = F_U1 + (size_t)16*64*1024;       // (16,64,32,32)
constexpr size_t F_S2 = F_S3 + (size_t)16*64*1024;       // (16,64,64,64)
constexpr size_t F_S1 = F_S2 + (size_t)16*64*4096;       // (16,64,128,128)
constexpr size_t C_0  = F_S1 + (size_t)16*64*16384;      // (16,64,  6,  6)
constexpr size_t C_1  = C_0  + (size_t)16*64*36;         // (16,64, 14, 14)
constexpr size_t C_2  = C_1  + (size_t)16*64*196;        // (16,64, 30, 30)
constexpr size_t C_3  = C_2  + (size_t)16*64*900;        // (16,64,126,126)
constexpr size_t A_1  = C_3  + (size_t)16*64*15876;      // (16,127,127)
constexpr size_t A_2  = A_1  + (size_t)16*127*127;
constexpr size_t A_3  = A_2  + (size_t)16*127*127;
constexpr size_t STATS = A_3 + (size_t)16*127*127;       // 2048 floats
constexpr size_t WS_FLOATS = STATS + 2048;

// ---------------- 1x1 conv + bias (pre-BN) ----------------
template<int CIN>
__global__ __launch_bounds__(256) void conv1x1_kernel(
    const float* __restrict__ in, const float* __restrict__ w,
    const float* __restrict__ bias, float* __restrict__ out, int HW)
{
    __shared__ __align__(16) float wl[64][64];   // [ci][co] chunk
    const int n = blockIdx.y;
    const int p = blockIdx.x * 256 + threadIdx.x;
    const bool act = (p < HW);
    float4 acc[16];
    #pragma unroll
    for (int i = 0; i < 16; ++i) acc[i] = make_float4(0.f, 0.f, 0.f, 0.f);
    const float* inp = in + (size_t)n * CIN * HW + p;
    for (int cb = 0; cb < CIN; cb += 64) {
        __syncthreads();
        #pragma unroll
        for (int t = 0; t < 16; ++t) {
            int e = threadIdx.x + t * 256;
            int ci = e >> 6, co = e & 63;
            wl[ci][co] = w[(size_t)co * CIN + cb + ci];
        }
        __syncthreads();
        if (act) {
            #pragma unroll 4
            for (int ci = 0; ci < 64; ++ci) {
                float x = inp[(size_t)(cb + ci) * HW];
                const float4* wp = (const float4*)(&wl[ci][0]);
                #pragma unroll
                for (int j = 0; j < 16; ++j) {
                    float4 wv = wp[j];
                    acc[j].x += wv.x * x; acc[j].y += wv.y * x;
                    acc[j].z += wv.z * x; acc[j].w += wv.w * x;
                }
            }
        }
    }
    if (act) {
        float* op = out + (size_t)n * 64 * HW + p;
        #pragma unroll
        for (int j = 0; j < 16; ++j) {
            op[(size_t)(4*j+0)*HW] = acc[j].x + bias[4*j+0];
            op[(size_t)(4*j+1)*HW] = acc[j].y + bias[4*j+1];
            op[(size_t)(4*j+2)*HW] = acc[j].z + bias[4*j+2];
            op[(size_t)(4*j+3)*HW] = acc[j].w + bias[4*j+3];
        }
    }
}

// ---------------- block reduce (sum, sumsq), blockDim.x == 256 ----------------
__device__ __forceinline__ void block_red2(float& s, float& s2)
{
    #pragma unroll
    for (int off = 32; off > 0; off >>= 1) {
        s  += __shfl_down(s,  off);
        s2 += __shfl_down(s2, off);
    }
    __shared__ float r[16];
    int wv = threadIdx.x >> 6;
    if ((threadIdx.x & 63) == 0) { r[wv] = s; r[8 + wv] = s2; }
    __syncthreads();
    if (threadIdx.x == 0) {
        s  = r[0] + r[1] + r[2] + r[3];
        s2 = r[8] + r[9] + r[10] + r[11];
    }
}

__global__ __launch_bounds__(256) void bn_stats_kernel(
    const float* __restrict__ x, float* __restrict__ st, int HW)
{
    const int c = blockIdx.x, n = blockIdx.y;
    const float* xc = x + ((size_t)n * 64 + c) * HW;
    float s = 0.f, s2 = 0.f;
    for (int p = threadIdx.x; p < HW; p += 256) { float v = xc[p]; s += v; s2 += v * v; }
    block_red2(s, s2);
    if (threadIdx.x == 0) { atomicAdd(&st[c], s); atomicAdd(&st[64 + c], s2); }
}

__global__ __launch_bounds__(256) void bn_apply_kernel(
    float* __restrict__ x, const float* __restrict__ st,
    const float* __restrict__ g, const float* __restrict__ b,
    int HW, float invCnt)
{
    const int total = 16 * 64 * HW;
    for (int idx = blockIdx.x * 256 + threadIdx.x; idx < total; idx += gridDim.x * 256) {
        int c = (idx / HW) & 63;
        float m = st[c] * invCnt;
        float v = st[64 + c] * invCnt - m * m;
        float inv = 1.0f / sqrtf(v + EPS);
        x[idx] = g[c] * (x[idx] - m) * inv + b[c];
    }
}

__global__ __launch_bounds__(256) void bn_upadd_kernel(
    float* __restrict__ x2, const float* __restrict__ u1,
    const float* __restrict__ st, const float* __restrict__ g,
    const float* __restrict__ b, int H2, float invCnt)
{
    const int W2 = H2, H1 = H2 >> 1, W1 = H1;
    const int total = 16 * 64 * H2 * W2;
    for (int idx = blockIdx.x * 256 + threadIdx.x; idx < total; idx += gridDim.x * 256) {
        int xx = idx % W2;
        int t = idx / W2;
        int yy = t % H2; t /= H2;
        int c = t & 63, n = t >> 6;
        float m = st[c] * invCnt;
        float v = st[64 + c] * invCnt - m * m;
        float val = g[c] * (x2[idx] - m) / sqrtf(v + EPS) + b[c];
        float hy = fminf(fmaxf(yy * 0.5f - 0.25f, 0.f), (float)(H1 - 1));
        float wx = fminf(fmaxf(xx * 0.5f - 0.25f, 0.f), (float)(W1 - 1));
        int h0 = (int)hy, w0 = (int)wx;
        int h1 = (h0 + 1 < H1) ? h0 + 1 : H1 - 1;
        int w1 = (w0 + 1 < W1) ? w0 + 1 : W1 - 1;
        float th = hy - h0, tw = wx - w0;
        const float* up = u1 + ((size_t)n * 64 + c) * H1 * W1;
        float v00 = up[h0 * W1 + w0], v01 = up[h0 * W1 + w1];
        float v10 = up[h1 * W1 + w0], v11 = up[h1 * W1 + w1];
        float bi = (v00 * (1.f - tw) + v01 * tw) * (1.f - th)
                 + (v10 * (1.f - tw) + v11 * tw) * th;
        x2[idx] = val + bi;
    }
}

// ---------------- 3x3 VALID conv + bias (pre-BN), 64->64 ch ----------------
__global__ __launch_bounds__(256) void conv3x3_kernel(
    const float* __restrict__ in, const float* __restrict__ w,
    const float* __restrict__ bias, float* __restrict__ out,
    int H, int tilesX)
{
    const int W = H, OH = H - 2, OW = W - 2;
    __shared__ __align__(16) float xs[8][18][19];
    __shared__ __align__(16) float wsm[8][9][64];   // [ci][tap][co]
    const int n = blockIdx.y;
    const int ty0 = (blockIdx.x / tilesX) * 16, tx0 = (blockIdx.x % tilesX) * 16;
    const int lx = threadIdx.x & 15, ly = threadIdx.x >> 4;
    const int oy = ty0 + ly, ox = tx0 + lx;
    const bool act = (oy < OH) && (ox < OW);
    float4 acc[16];
    #pragma unroll
    for (int i = 0; i < 16; ++i) acc[i] = make_float4(0.f, 0.f, 0.f, 0.f);
    for (int cb = 0; cb < 64; cb += 8) {
        __syncthreads();
        for (int t = threadIdx.x; t < 8 * 18 * 18; t += 256) {
            int ci = t / 324, r = t % 324;
            int yy = r / 18, xx = r % 18;
            int gy = ty0 + yy, gx = tx0 + xx;
            float v = 0.f;
            if (gy < H && gx < W) v = in[(((size_t)n * 64 + cb + ci) * H + gy) * W + gx];
            xs[ci][yy][xx] = v;
        }
        for (int t = threadIdx.x; t < 8 * 9 * 64; t += 256) {
            int ci = t / 576, r = t % 576;
            int k = r >> 6, co = r & 63;
            wsm[ci][k][co] = w[(((size_t)co * 64) + cb + ci) * 9 + k];
        }
        __syncthreads();
        #pragma unroll
        for (int ci = 0; ci < 8; ++ci) {
            float xv[9];
            #pragma unroll
            for (int dy = 0; dy < 3; ++dy)
                #pragma unroll
                for (int dx = 0; dx < 3; ++dx)
                    xv[dy * 3 + dx] = xs[ci][ly + dy][lx + dx];
            #pragma unroll
            for (int k = 0; k < 9; ++k) {
                const float4* wp = (const float4*)(&wsm[ci][k][0]);
                float xk = xv[k];
                #pragma unroll
                for (int j = 0; j < 16; ++j) {
                    float4 wv = wp[j];
                    acc[j].x += wv.x * xk; acc[j].y += wv.y * xk;
                    acc[j].z += wv.z * xk; acc[j].w += wv.w * xk;
                }
            }
        }
    }
    if (act) {
        #pragma unroll
        for (int j = 0; j < 16; ++j) {
            out[(((size_t)n * 64 + 4*j+0) * OH + oy) * OW + ox] = acc[j].x + bias[4*j+0];
            out[(((size_t)n * 64 + 4*j+1) * OH + oy) * OW + ox] = acc[j].y + bias[4*j+1];
            out[(((size_t)n * 64 + 4*j+2) * OH + oy) * OW + ox] = acc[j].z + bias[4*j+2];
            out[(((size_t)n * 64 + 4*j+3) * OH + oy) * OW + ox] = acc[j].w + bias[4*j+3];
        }
    }
}

// ---------------- correlation v2 ----------------
// out[b][y][x] += sum_{ci in z-slice} sum_{ky,kx} q[b][ci][ky][kx] *
//                 spad[b][ci][y+ky][x+kx]   (spad = smap zero-padded by QH/2)
// Inner loop: q row held in registers; ONE LDS read per window position t
// feeds 8 FMAs acc[j] += qr[t-j]*sv (static register indices, no shifts).
template<int QH, int ZSPLIT>
__global__ __launch_bounds__(256) void corr2_kernel(
    const float* __restrict__ q, const float* __restrict__ smap,
    float* __restrict__ outA)
{
    constexpr int PAD = QH / 2;
    constexpr int SH = 16 + QH - 1;
    constexpr int SW = 128 + QH - 1;   // used width
    constexpr int RS = SW | 1;         // odd row stride (bank spread across rows)
    __shared__ float stile[SH * RS];
    __shared__ float qs[QH * QH];
    const int b = blockIdx.y;
    const int by0 = blockIdx.x * 16;
    const int lxg = threadIdx.x & 15, ly = threadIdx.x >> 4;
    const int y = by0 + ly, X0 = lxg * 8;
    constexpr int ciN = 64 / ZSPLIT;
    const int ci0 = blockIdx.z * ciN;
    float acc[8];
    #pragma unroll
    for (int j = 0; j < 8; ++j) acc[j] = 0.f;
    for (int ci = ci0; ci < ci0 + ciN; ++ci) {
        __syncthreads();
        const float* sp = smap + ((size_t)b * 64 + ci) * 126 * 126;
        for (int t = threadIdx.x; t < SH * SW; t += 256) {
            int yy = t / SW, xx = t % SW;
            int sy = by0 + yy - PAD, sx = xx - PAD;
            float v = 0.f;
            if (sy >= 0 && sy < 126 && sx >= 0 && sx < 126) v = sp[sy * 126 + sx];
            stile[yy * RS + xx] = v;
        }
        const float* qp = q + ((size_t)b * 64 + ci) * QH * QH;
        for (int t = threadIdx.x; t < QH * QH; t += 256) qs[t] = qp[t];
        __syncthreads();
        #pragma unroll 1
        for (int ky = 0; ky < QH; ++ky) {
            float qr[QH];
            #pragma unroll
            for (int k = 0; k < QH; ++k) qr[k] = qs[ky * QH + k];
            const float* srow = &stile[(ly + ky) * RS + X0];
            #pragma unroll
            for (int t = 0; t < QH + 7; ++t) {
                float sv = srow[t];
                #pragma unroll
                for (int j = 0; j < 8; ++j) {
                    int k = t - j;
                    if (k >= 0 && k < QH) acc[j] = fmaf(qr[k], sv, acc[j]);
                }
            }
        }
    }
    if (y < 127) {
        float* op = outA + ((size_t)b * 127 + y) * 127;
        #pragma unroll
        for (int j = 0; j < 8; ++j)
            if (X0 + j < 127) atomicAdd(&op[X0 + j], acc[j]);
    }
}

// whole-tensor sum/sumsq
__global__ __launch_bounds__(256) void scalar_stats_kernel(
    const float* __restrict__ x, float* __restrict__ st, int total)
{
    float s = 0.f, s2 = 0.f;
    for (int i = blockIdx.x * 256 + threadIdx.x; i < total; i += gridDim.x * 256) {
        float v = x[i]; s += v; s2 += v * v;
    }
    block_red2(s, s2);
    if (threadIdx.x == 0) { atomicAdd(&st[0], s); atomicAdd(&st[1], s2); }
}

// normalize each A, softmax-weighted fuse, bilinear 127->128 (align_corners=True)
__global__ __launch_bounds__(256) void final_kernel(
    const float* __restrict__ A1p, const float* __restrict__ A2p,
    const float* __restrict__ A3p, const float* __restrict__ st,
    const float* __restrict__ cg, const float* __restrict__ cbv,
    const float* __restrict__ fwp, float* __restrict__ out)
{
    int idx = blockIdx.x * 256 + threadIdx.x;
    if (idx >= 16 * 128 * 128) return;
    int x = idx & 127, y = (idx >> 7) & 127, n = idx >> 14;
    float f0 = fwp[0], f1 = fwp[1], f2 = fwp[2];
    float mx = fmaxf(fmaxf(f0, f1), f2);
    float e0 = expf(f0 - mx), e1 = expf(f1 - mx), e2 = expf(f2 - mx);
    float inv = 1.f / (e0 + e1 + e2);
    float wgt[3] = { e0 * inv, e1 * inv, e2 * inv };
    const float invCnt = 1.f / 258064.f;
    float coef[3], K = 0.f;
    #pragma unroll
    for (int a = 0; a < 3; ++a) {
        float m = st[2 * a] * invCnt;
        float v = st[2 * a + 1] * invCnt - m * m;
        float sc = cg[a] / sqrtf(v + EPS);
        coef[a] = wgt[a] * sc;
        K += wgt[a] * (cbv[a] - sc * m);
    }
    float s = (float)(126.0 / 127.0);
    float hy = y * s, wx = x * s;
    int h0 = (int)hy, w0 = (int)wx;
    int h1 = (h0 + 1 < 127) ? h0 + 1 : 126;
    int w1 = (w0 + 1 < 127) ? w0 + 1 : 126;
    float th = hy - h0, tw = wx - w0;
    const float* As[3] = { A1p, A2p, A3p };
    float val = K;
    #pragma unroll
    for (int a = 0; a < 3; ++a) {
        const float* Ab = As[a] + (size_t)n * 127 * 127;
        float v00 = Ab[h0 * 127 + w0], v01 = Ab[h0 * 127 + w1];
        float v10 = Ab[h1 * 127 + w0], v11 = Ab[h1 * 127 + w1];
        val += coef[a] * ((v00 * (1.f - tw) + v01 * tw) * (1.f - th)
                        + (v10 * (1.f - tw) + v11 * tw) * th);
    }
    out[idx] = val;
}

static inline int nblk(long long total) {
    long long b = (total + 255) / 256;
    return (int)(b < 2048 ? b : 2048);
}

extern "C" void kernel_launch(void* const* d_in, const int* in_sizes, int n_in,
                              void* d_out, int out_size, void* d_ws, size_t ws_size,
                              hipStream_t stream)
{
    const float* sat1 = (const float*)d_in[0];
    const float* sat2 = (const float*)d_in[1];
    const float* sat3 = (const float*)d_in[2];
    const float* uav1 = (const float*)d_in[3];
    const float* uav2 = (const float*)d_in[4];
    const float* uav3 = (const float*)d_in[5];
    const float* c1w = (const float*)d_in[6];
    const float* c1b = (const float*)d_in[7];
    const float* b1g = (const float*)d_in[8];
    const float* b1b = (const float*)d_in[9];
    const float* c2w = (const float*)d_in[10];
    const float* c2b = (const float*)d_in[11];
    const float* b2g = (const float*)d_in[12];
    const float* b2b = (const float*)d_in[13];
    const float* c3w = (const float*)d_in[14];
    const float* c3b = (const float*)d_in[15];
    const float* b3g = (const float*)d_in[16];
    const float* b3b = (const float*)d_in[17];
    const float* cuw = (const float*)d_in[18];
    const float* cub = (const float*)d_in[19];
    const float* bug = (const float*)d_in[20];
    const float* bub = (const float*)d_in[21];
    const float* corr_g = (const float*)d_in[22];
    const float* corr_b = (const float*)d_in[23];
    const float* fusion_w = (const float*)d_in[24];
    float* ws = (float*)d_ws;
    float* out = (float*)d_out;
    float* ST = ws + STATS;

    // zero A1..A3 + STATS (contiguous tail of the layout)
    hipMemsetAsync(ws + A_1, 0, (WS_FLOATS - A_1) * sizeof(float), stream);

    // ---- 1x1 convs (pre-BN) ----
    conv1x1_kernel<512><<<dim3(1, 16), 256, 0, stream>>>(uav3, c1w,            c1b,      ws + F_U3, 64);
    conv1x1_kernel<256><<<dim3(1, 16), 256, 0, stream>>>(uav2, c2w,            c2b,      ws + F_U2, 256);
    conv1x1_kernel<128><<<dim3(4, 16), 256, 0, stream>>>(uav1, c3w,            c3b,      ws + F_U1, 1024);
    conv1x1_kernel<512><<<dim3(4, 16), 256, 0, stream>>>(sat3, c1w + 64 * 512, c1b + 64, ws + F_S3, 1024);
    conv1x1_kernel<256><<<dim3(16, 16), 256, 0, stream>>>(sat2, c2w + 64 * 256, c2b + 64, ws + F_S2, 4096);
    conv1x1_kernel<128><<<dim3(64, 16), 256, 0, stream>>>(sat1, c3w + 64 * 128, c3b + 64, ws + F_S1, 16384);

    // ---- BN stats (pre-BN tensors) ----
    bn_stats_kernel<<<dim3(64, 16), 256, 0, stream>>>(ws + F_U3, ST + 0 * 128, 64);
    bn_stats_kernel<<<dim3(64, 16), 256, 0, stream>>>(ws + F_U2, ST + 1 * 128, 256);
    bn_stats_kernel<<<dim3(64, 16), 256, 0, stream>>>(ws + F_U1, ST + 2 * 128, 1024);
    bn_stats_kernel<<<dim3(64, 16), 256, 0, stream>>>(ws + F_S3, ST + 3 * 128, 1024);
    bn_stats_kernel<<<dim3(64, 16), 256, 0, stream>>>(ws + F_S2, ST + 4 * 128, 4096);
    bn_stats_kernel<<<dim3(64, 16), 256, 0, stream>>>(ws + F_S1, ST + 5 * 128, 16384);

    // ---- top-down pyramid (BN in place; upsample-add fused) ----
    bn_apply_kernel<<<nblk(16*64*64), 256, 0, stream>>>(ws + F_U3, ST + 0 * 128, b1g,      b1b,      64,   1.f / 1024.f);
    bn_apply_kernel<<<nblk(16*64*1024), 256, 0, stream>>>(ws + F_S3, ST + 3 * 128, b1g + 64, b1b + 64, 1024, 1.f / 16384.f);
    bn_upadd_kernel<<<nblk(16*64*256), 256, 0, stream>>>(ws + F_U2, ws + F_U3, ST + 1 * 128, b2g,      b2b,      16,  1.f / 4096.f);
    bn_upadd_kernel<<<nblk(16*64*4096), 256, 0, stream>>>(ws + F_S2, ws + F_S3, ST + 4 * 128, b2g + 64, b2b + 64, 64,  1.f / 65536.f);
    bn_upadd_kernel<<<nblk(16*64*1024), 256, 0, stream>>>(ws + F_U1, ws + F_U2, ST + 2 * 128, b3g,      b3b,      32,  1.f / 16384.f);
    bn_upadd_kernel<<<nblk(16*64*16384), 256, 0, stream>>>(ws + F_S1, ws + F_S2, ST + 5 * 128, b3g + 64, b3b + 64, 128, 1.f / 262144.f);

    // ---- 3x3 convs (pre-BN) ----
    conv3x3_kernel<<<dim3(1, 16), 256, 0, stream>>>(ws + F_U3, cuw + 0 * 64 * 64 * 9, cub + 0,   ws + C_0, 8, 1);
    conv3x3_kernel<<<dim3(1, 16), 256, 0, stream>>>(ws + F_U2, cuw + 1 * 64 * 64 * 9, cub + 64,  ws + C_1, 16, 1);
    conv3x3_kernel<<<dim3(4, 16), 256, 0, stream>>>(ws + F_U1, cuw + 2 * 64 * 64 * 9, cub + 128, ws + C_2, 32, 2);
    conv3x3_kernel<<<dim3(64, 16), 256, 0, stream>>>(ws + F_S1, cuw + 3 * 64 * 64 * 9, cub + 192, ws + C_3, 128, 8);

    bn_stats_kernel<<<dim3(64, 16), 256, 0, stream>>>(ws + C_0, ST + 768 + 0 * 128, 36);
    bn_stats_kernel<<<dim3(64, 16), 256, 0, stream>>>(ws + C_1, ST + 768 + 1 * 128, 196);
    bn_stats_kernel<<<dim3(64, 16), 256, 0, stream>>>(ws + C_2, ST + 768 + 2 * 128, 900);
    bn_stats_kernel<<<dim3(64, 16), 256, 0, stream>>>(ws + C_3, ST + 768 + 3 * 128, 15876);

    bn_apply_kernel<<<nblk(16*64*36), 256, 0, stream>>>(ws + C_0, ST + 768 + 0 * 128, bug,       bub,       36,    1.f / 576.f);
    bn_apply_kernel<<<nblk(16*64*196), 256, 0, stream>>>(ws + C_1, ST + 768 + 1 * 128, bug + 64,  bub + 64,  196,   1.f / 3136.f);
    bn_apply_kernel<<<nblk(16*64*900), 256, 0, stream>>>(ws + C_2, ST + 768 + 2 * 128, bug + 128, bub + 128, 900,   1.f / 14400.f);
    bn_apply_kernel<<<nblk(16*64*15876), 256, 0, stream>>>(ws + C_3, ST + 768 + 3 * 128, bug + 192, bub + 192, 15876, 1.f / 254016.f);

    // ---- correlations v2 (atomicAdd into zeroed A buffers; ci split over z) ----
    corr2_kernel<6, 4> <<<dim3(8, 16, 4), 256, 0, stream>>>(ws + C_0, ws + C_3, ws + A_1);
    corr2_kernel<14, 8><<<dim3(8, 16, 8), 256, 0, stream>>>(ws + C_1, ws + C_3, ws + A_2);
    corr2_kernel<30, 8><<<dim3(8, 16, 8), 256, 0, stream>>>(ws + C_2, ws + C_3, ws + A_3);

    scalar_stats_kernel<<<512, 256, 0, stream>>>(ws + A_1, ST + 1280 + 0, 258064);
    scalar_stats_kernel<<<512, 256, 0, stream>>>(ws + A_2, ST + 1280 + 2, 258064);
    scalar_stats_kernel<<<512, 256, 0, stream>>>(ws + A_3, ST + 1280 + 4, 258064);

    final_kernel<<<1024, 256, 0, stream>>>(ws + A_1, ws + A_2, ws + A_3,
                                           ST + 1280, corr_g, corr_b, fusion_w, out);
}

// Round 3
// 2908.855 us; speedup vs baseline: 1.1668x; 1.1668x over previous
//
#include <hip/hip_runtime.h>

#define EPS 1e-5f

// ---------------- workspace layout (float offsets) ----------------
constexpr size_t F_U3 = 0;                               // (16,64, 8, 8)
constexpr size_t F_U2 = F_U3 + (size_t)16*64*64;         // (16,64,16,16)
constexpr size_t F_U1 = F_U2 + (size_t)16*64*256;        // (16,64,32,32)
constexpr size_t F_S3 = F_U1 + (size_t)16*64*1024;       // (16,64,32,32)
constexpr size_t F_S2 = F_S3 + (size_t)16*64*1024;       // (16,64,64,64)
constexpr size_t F_S1 = F_S2 + (size_t)16*64*4096;       // (16,64,128,128)
constexpr size_t C_0  = F_S1 + (size_t)16*64*16384;      // (16,64,  6,  6)
constexpr size_t C_1  = C_0  + (size_t)16*64*36;         // (16,64, 14, 14)
constexpr size_t C_2  = C_1  + (size_t)16*64*196;        // (16,64, 30, 30)
constexpr size_t C_3  = C_2  + (size_t)16*64*900;        // (16,64,126,126)
constexpr size_t A_1  = C_3  + (size_t)16*64*15876;      // (16,127,127)
constexpr size_t A_2  = A_1  + (size_t)16*127*127;
constexpr size_t A_3  = A_2  + (size_t)16*127*127;
constexpr size_t STATS = A_3 + (size_t)16*127*127;       // 2048 floats
constexpr size_t WS_FLOATS = STATS + 2048;

// ---------------- 1x1 conv + bias (pre-BN) ----------------
template<int CIN>
__global__ __launch_bounds__(256) void conv1x1_kernel(
    const float* __restrict__ in, const float* __restrict__ w,
    const float* __restrict__ bias, float* __restrict__ out, int HW)
{
    __shared__ __align__(16) float wl[64][64];   // [ci][co] chunk
    const int n = blockIdx.y;
    const int p = blockIdx.x * 256 + threadIdx.x;
    const bool act = (p < HW);
    float4 acc[16];
    #pragma unroll
    for (int i = 0; i < 16; ++i) acc[i] = make_float4(0.f, 0.f, 0.f, 0.f);
    const float* inp = in + (size_t)n * CIN * HW + p;
    for (int cb = 0; cb < CIN; cb += 64) {
        __syncthreads();
        #pragma unroll
        for (int t = 0; t < 16; ++t) {
            int e = threadIdx.x + t * 256;
            int ci = e >> 6, co = e & 63;
            wl[ci][co] = w[(size_t)co * CIN + cb + ci];
        }
        __syncthreads();
        if (act) {
            #pragma unroll 4
            for (int ci = 0; ci < 64; ++ci) {
                float x = inp[(size_t)(cb + ci) * HW];
                const float4* wp = (const float4*)(&wl[ci][0]);
                #pragma unroll
                for (int j = 0; j < 16; ++j) {
                    float4 wv = wp[j];
                    acc[j].x += wv.x * x; acc[j].y += wv.y * x;
                    acc[j].z += wv.z * x; acc[j].w += wv.w * x;
                }
            }
        }
    }
    if (act) {
        float* op = out + (size_t)n * 64 * HW + p;
        #pragma unroll
        for (int j = 0; j < 16; ++j) {
            op[(size_t)(4*j+0)*HW] = acc[j].x + bias[4*j+0];
            op[(size_t)(4*j+1)*HW] = acc[j].y + bias[4*j+1];
            op[(size_t)(4*j+2)*HW] = acc[j].z + bias[4*j+2];
            op[(size_t)(4*j+3)*HW] = acc[j].w + bias[4*j+3];
        }
    }
}

// ---------------- block reduce (sum, sumsq), blockDim.x == 256 ----------------
__device__ __forceinline__ void block_red2(float& s, float& s2)
{
    #pragma unroll
    for (int off = 32; off > 0; off >>= 1) {
        s  += __shfl_down(s,  off);
        s2 += __shfl_down(s2, off);
    }
    __shared__ float r[16];
    int wv = threadIdx.x >> 6;
    if ((threadIdx.x & 63) == 0) { r[wv] = s; r[8 + wv] = s2; }
    __syncthreads();
    if (threadIdx.x == 0) {
        s  = r[0] + r[1] + r[2] + r[3];
        s2 = r[8] + r[9] + r[10] + r[11];
    }
}

__global__ __launch_bounds__(256) void bn_stats_kernel(
    const float* __restrict__ x, float* __restrict__ st, int HW)
{
    const int c = blockIdx.x, n = blockIdx.y;
    const float* xc = x + ((size_t)n * 64 + c) * HW;
    float s = 0.f, s2 = 0.f;
    for (int p = threadIdx.x; p < HW; p += 256) { float v = xc[p]; s += v; s2 += v * v; }
    block_red2(s, s2);
    if (threadIdx.x == 0) { atomicAdd(&st[c], s); atomicAdd(&st[64 + c], s2); }
}

__global__ __launch_bounds__(256) void bn_apply_kernel(
    float* __restrict__ x, const float* __restrict__ st,
    const float* __restrict__ g, const float* __restrict__ b,
    int HW, float invCnt)
{
    const int total = 16 * 64 * HW;
    for (int idx = blockIdx.x * 256 + threadIdx.x; idx < total; idx += gridDim.x * 256) {
        int c = (idx / HW) & 63;
        float m = st[c] * invCnt;
        float v = st[64 + c] * invCnt - m * m;
        float inv = 1.0f / sqrtf(v + EPS);
        x[idx] = g[c] * (x[idx] - m) * inv + b[c];
    }
}

__global__ __launch_bounds__(256) void bn_upadd_kernel(
    float* __restrict__ x2, const float* __restrict__ u1,
    const float* __restrict__ st, const float* __restrict__ g,
    const float* __restrict__ b, int H2, float invCnt)
{
    const int W2 = H2, H1 = H2 >> 1, W1 = H1;
    const int total = 16 * 64 * H2 * W2;
    for (int idx = blockIdx.x * 256 + threadIdx.x; idx < total; idx += gridDim.x * 256) {
        int xx = idx % W2;
        int t = idx / W2;
        int yy = t % H2; t /= H2;
        int c = t & 63, n = t >> 6;
        float m = st[c] * invCnt;
        float v = st[64 + c] * invCnt - m * m;
        float val = g[c] * (x2[idx] - m) / sqrtf(v + EPS) + b[c];
        float hy = fminf(fmaxf(yy * 0.5f - 0.25f, 0.f), (float)(H1 - 1));
        float wx = fminf(fmaxf(xx * 0.5f - 0.25f, 0.f), (float)(W1 - 1));
        int h0 = (int)hy, w0 = (int)wx;
        int h1 = (h0 + 1 < H1) ? h0 + 1 : H1 - 1;
        int w1 = (w0 + 1 < W1) ? w0 + 1 : W1 - 1;
        float th = hy - h0, tw = wx - w0;
        const float* up = u1 + ((size_t)n * 64 + c) * H1 * W1;
        float v00 = up[h0 * W1 + w0], v01 = up[h0 * W1 + w1];
        float v10 = up[h1 * W1 + w0], v11 = up[h1 * W1 + w1];
        float bi = (v00 * (1.f - tw) + v01 * tw) * (1.f - th)
                 + (v10 * (1.f - tw) + v11 * tw) * th;
        x2[idx] = val + bi;
    }
}

// ---------------- 3x3 VALID conv + bias (pre-BN), 64->64 ch ----------------
__global__ __launch_bounds__(256) void conv3x3_kernel(
    const float* __restrict__ in, const float* __restrict__ w,
    const float* __restrict__ bias, float* __restrict__ out,
    int H, int tilesX)
{
    const int W = H, OH = H - 2, OW = W - 2;
    __shared__ __align__(16) float xs[8][18][19];
    __shared__ __align__(16) float wsm[8][9][64];   // [ci][tap][co]
    const int n = blockIdx.y;
    const int ty0 = (blockIdx.x / tilesX) * 16, tx0 = (blockIdx.x % tilesX) * 16;
    const int lx = threadIdx.x & 15, ly = threadIdx.x >> 4;
    const int oy = ty0 + ly, ox = tx0 + lx;
    const bool act = (oy < OH) && (ox < OW);
    float4 acc[16];
    #pragma unroll
    for (int i = 0; i < 16; ++i) acc[i] = make_float4(0.f, 0.f, 0.f, 0.f);
    for (int cb = 0; cb < 64; cb += 8) {
        __syncthreads();
        for (int t = threadIdx.x; t < 8 * 18 * 18; t += 256) {
            int ci = t / 324, r = t % 324;
            int yy = r / 18, xx = r % 18;
            int gy = ty0 + yy, gx = tx0 + xx;
            float v = 0.f;
            if (gy < H && gx < W) v = in[(((size_t)n * 64 + cb + ci) * H + gy) * W + gx];
            xs[ci][yy][xx] = v;
        }
        for (int t = threadIdx.x; t < 8 * 9 * 64; t += 256) {
            int ci = t / 576, r = t % 576;
            int k = r >> 6, co = r & 63;
            wsm[ci][k][co] = w[(((size_t)co * 64) + cb + ci) * 9 + k];
        }
        __syncthreads();
        #pragma unroll
        for (int ci = 0; ci < 8; ++ci) {
            float xv[9];
            #pragma unroll
            for (int dy = 0; dy < 3; ++dy)
                #pragma unroll
                for (int dx = 0; dx < 3; ++dx)
                    xv[dy * 3 + dx] = xs[ci][ly + dy][lx + dx];
            #pragma unroll
            for (int k = 0; k < 9; ++k) {
                const float4* wp = (const float4*)(&wsm[ci][k][0]);
                float xk = xv[k];
                #pragma unroll
                for (int j = 0; j < 16; ++j) {
                    float4 wv = wp[j];
                    acc[j].x += wv.x * xk; acc[j].y += wv.y * xk;
                    acc[j].z += wv.z * xk; acc[j].w += wv.w * xk;
                }
            }
        }
    }
    if (act) {
        #pragma unroll
        for (int j = 0; j < 16; ++j) {
            out[(((size_t)n * 64 + 4*j+0) * OH + oy) * OW + ox] = acc[j].x + bias[4*j+0];
            out[(((size_t)n * 64 + 4*j+1) * OH + oy) * OW + ox] = acc[j].y + bias[4*j+1];
            out[(((size_t)n * 64 + 4*j+2) * OH + oy) * OW + ox] = acc[j].z + bias[4*j+2];
            out[(((size_t)n * 64 + 4*j+3) * OH + oy) * OW + ox] = acc[j].w + bias[4*j+3];
        }
    }
}

// ---------------- correlation v3 ----------------
// Bank-conflict-free: LDS s-tile stored with pad-every-16 swizzle
// g(x) = x + (x>>4); lane bases 8l+(8l>>4) hit 16 distinct banks per
// 16-lane group (2-way max across groups = free). Read addresses are
// base0/base1 + compile-time immediate (zero extra VALU):
//   g(X0+t) = X0s + t + (t>>4) + p*[(t&15)>=8],  p=(X0>>3)&1.
// q is wave-uniform -> scalar loads from global (no LDS), FMA with SGPR.
template<int QH, int ZSPLIT>
__global__ __launch_bounds__(256) void corr3_kernel(
    const float* __restrict__ q, const float* __restrict__ smap,
    float* __restrict__ outA)
{
    constexpr int PAD = QH / 2;
    constexpr int SH = 16 + QH - 1;
    constexpr int SW = 128 + QH - 1;                    // odd (QH even)
    constexpr int RS = (SW + ((SW - 1) >> 4) + 1) | 1;  // swizzled row stride
    __shared__ float stile[SH * RS];
    const int b = blockIdx.y;
    const int by0 = blockIdx.x * 16;
    const int lxg = threadIdx.x & 15, ly = threadIdx.x >> 4;
    const int y = by0 + ly;
    const int X0 = lxg * 8;
    const int X0s = X0 + (X0 >> 4);
    const int p = (X0 >> 3) & 1;
    constexpr int ciN = 64 / ZSPLIT;
    const int ci0 = blockIdx.z * ciN;
    float acc[8];
    #pragma unroll
    for (int j = 0; j < 8; ++j) acc[j] = 0.f;
    for (int ci = ci0; ci < ci0 + ciN; ++ci) {
        __syncthreads();
        const float* sp = smap + ((size_t)b * 64 + ci) * 126 * 126;
        for (int t = threadIdx.x; t < SH * SW; t += 256) {
            int yy = t / SW, xx = t % SW;
            int sy = by0 + yy - PAD, sx = xx - PAD;
            float v = 0.f;
            if (sy >= 0 && sy < 126 && sx >= 0 && sx < 126) v = sp[sy * 126 + sx];
            stile[yy * RS + xx + (xx >> 4)] = v;
        }
        __syncthreads();
        const float* qp = q + ((size_t)b * 64 + ci) * QH * QH;
        #pragma unroll 1
        for (int ky = 0; ky < QH; ++ky) {
            float qr[QH];
            #pragma unroll
            for (int k = 0; k < QH; ++k) qr[k] = qp[ky * QH + k];
            const float* b0 = &stile[(ly + ky) * RS + X0s];
            const float* b1 = b0 + p;
            #pragma unroll
            for (int t = 0; t < QH + 7; ++t) {
                float sv = (((t & 15) >= 8) ? b1 : b0)[t + (t >> 4)];
                #pragma unroll
                for (int j = 0; j < 8; ++j) {
                    int k = t - j;
                    if (k >= 0 && k < QH) acc[j] = fmaf(qr[k], sv, acc[j]);
                }
            }
        }
    }
    if (y < 127) {
        float* op = outA + ((size_t)b * 127 + y) * 127;
        #pragma unroll
        for (int j = 0; j < 8; ++j)
            if (X0 + j < 127) atomicAdd(&op[X0 + j], acc[j]);
    }
}

// whole-tensor sum/sumsq
__global__ __launch_bounds__(256) void scalar_stats_kernel(
    const float* __restrict__ x, float* __restrict__ st, int total)
{
    float s = 0.f, s2 = 0.f;
    for (int i = blockIdx.x * 256 + threadIdx.x; i < total; i += gridDim.x * 256) {
        float v = x[i]; s += v; s2 += v * v;
    }
    block_red2(s, s2);
    if (threadIdx.x == 0) { atomicAdd(&st[0], s); atomicAdd(&st[1], s2); }
}

// normalize each A, softmax-weighted fuse, bilinear 127->128 (align_corners=True)
__global__ __launch_bounds__(256) void final_kernel(
    const float* __restrict__ A1p, const float* __restrict__ A2p,
    const float* __restrict__ A3p, const float* __restrict__ st,
    const float* __restrict__ cg, const float* __restrict__ cbv,
    const float* __restrict__ fwp, float* __restrict__ out)
{
    int idx = blockIdx.x * 256 + threadIdx.x;
    if (idx >= 16 * 128 * 128) return;
    int x = idx & 127, y = (idx >> 7) & 127, n = idx >> 14;
    float f0 = fwp[0], f1 = fwp[1], f2 = fwp[2];
    float mx = fmaxf(fmaxf(f0, f1), f2);
    float e0 = expf(f0 - mx), e1 = expf(f1 - mx), e2 = expf(f2 - mx);
    float inv = 1.f / (e0 + e1 + e2);
    float wgt[3] = { e0 * inv, e1 * inv, e2 * inv };
    const float invCnt = 1.f / 258064.f;
    float coef[3], K = 0.f;
    #pragma unroll
    for (int a = 0; a < 3; ++a) {
        float m = st[2 * a] * invCnt;
        float v = st[2 * a + 1] * invCnt - m * m;
        float sc = cg[a] / sqrtf(v + EPS);
        coef[a] = wgt[a] * sc;
        K += wgt[a] * (cbv[a] - sc * m);
    }
    float s = (float)(126.0 / 127.0);
    float hy = y * s, wx = x * s;
    int h0 = (int)hy, w0 = (int)wx;
    int h1 = (h0 + 1 < 127) ? h0 + 1 : 126;
    int w1 = (w0 + 1 < 127) ? w0 + 1 : 126;
    float th = hy - h0, tw = wx - w0;
    const float* As[3] = { A1p, A2p, A3p };
    float val = K;
    #pragma unroll
    for (int a = 0; a < 3; ++a) {
        const float* Ab = As[a] + (size_t)n * 127 * 127;
        float v00 = Ab[h0 * 127 + w0], v01 = Ab[h0 * 127 + w1];
        float v10 = Ab[h1 * 127 + w0], v11 = Ab[h1 * 127 + w1];
        val += coef[a] * ((v00 * (1.f - tw) + v01 * tw) * (1.f - th)
                        + (v10 * (1.f - tw) + v11 * tw) * th);
    }
    out[idx] = val;
}

static inline int nblk(long long total) {
    long long b = (total + 255) / 256;
    return (int)(b < 2048 ? b : 2048);
}

extern "C" void kernel_launch(void* const* d_in, const int* in_sizes, int n_in,
                              void* d_out, int out_size, void* d_ws, size_t ws_size,
                              hipStream_t stream)
{
    const float* sat1 = (const float*)d_in[0];
    const float* sat2 = (const float*)d_in[1];
    const float* sat3 = (const float*)d_in[2];
    const float* uav1 = (const float*)d_in[3];
    const float* uav2 = (const float*)d_in[4];
    const float* uav3 = (const float*)d_in[5];
    const float* c1w = (const float*)d_in[6];
    const float* c1b = (const float*)d_in[7];
    const float* b1g = (const float*)d_in[8];
    const float* b1b = (const float*)d_in[9];
    const float* c2w = (const float*)d_in[10];
    const float* c2b = (const float*)d_in[11];
    const float* b2g = (const float*)d_in[12];
    const float* b2b = (const float*)d_in[13];
    const float* c3w = (const float*)d_in[14];
    const float* c3b = (const float*)d_in[15];
    const float* b3g = (const float*)d_in[16];
    const float* b3b = (const float*)d_in[17];
    const float* cuw = (const float*)d_in[18];
    const float* cub = (const float*)d_in[19];
    const float* bug = (const float*)d_in[20];
    const float* bub = (const float*)d_in[21];
    const float* corr_g = (const float*)d_in[22];
    const float* corr_b = (const float*)d_in[23];
    const float* fusion_w = (const float*)d_in[24];
    float* ws = (float*)d_ws;
    float* out = (float*)d_out;
    float* ST = ws + STATS;

    // zero A1..A3 + STATS (contiguous tail of the layout)
    hipMemsetAsync(ws + A_1, 0, (WS_FLOATS - A_1) * sizeof(float), stream);

    // ---- 1x1 convs (pre-BN) ----
    conv1x1_kernel<512><<<dim3(1, 16), 256, 0, stream>>>(uav3, c1w,            c1b,      ws + F_U3, 64);
    conv1x1_kernel<256><<<dim3(1, 16), 256, 0, stream>>>(uav2, c2w,            c2b,      ws + F_U2, 256);
    conv1x1_kernel<128><<<dim3(4, 16), 256, 0, stream>>>(uav1, c3w,            c3b,      ws + F_U1, 1024);
    conv1x1_kernel<512><<<dim3(4, 16), 256, 0, stream>>>(sat3, c1w + 64 * 512, c1b + 64, ws + F_S3, 1024);
    conv1x1_kernel<256><<<dim3(16, 16), 256, 0, stream>>>(sat2, c2w + 64 * 256, c2b + 64, ws + F_S2, 4096);
    conv1x1_kernel<128><<<dim3(64, 16), 256, 0, stream>>>(sat1, c3w + 64 * 128, c3b + 64, ws + F_S1, 16384);

    // ---- BN stats (pre-BN tensors) ----
    bn_stats_kernel<<<dim3(64, 16), 256, 0, stream>>>(ws + F_U3, ST + 0 * 128, 64);
    bn_stats_kernel<<<dim3(64, 16), 256, 0, stream>>>(ws + F_U2, ST + 1 * 128, 256);
    bn_stats_kernel<<<dim3(64, 16), 256, 0, stream>>>(ws + F_U1, ST + 2 * 128, 1024);
    bn_stats_kernel<<<dim3(64, 16), 256, 0, stream>>>(ws + F_S3, ST + 3 * 128, 1024);
    bn_stats_kernel<<<dim3(64, 16), 256, 0, stream>>>(ws + F_S2, ST + 4 * 128, 4096);
    bn_stats_kernel<<<dim3(64, 16), 256, 0, stream>>>(ws + F_S1, ST + 5 * 128, 16384);

    // ---- top-down pyramid (BN in place; upsample-add fused) ----
    bn_apply_kernel<<<nblk(16*64*64), 256, 0, stream>>>(ws + F_U3, ST + 0 * 128, b1g,      b1b,      64,   1.f / 1024.f);
    bn_apply_kernel<<<nblk(16*64*1024), 256, 0, stream>>>(ws + F_S3, ST + 3 * 128, b1g + 64, b1b + 64, 1024, 1.f / 16384.f);
    bn_upadd_kernel<<<nblk(16*64*256), 256, 0, stream>>>(ws + F_U2, ws + F_U3, ST + 1 * 128, b2g,      b2b,      16,  1.f / 4096.f);
    bn_upadd_kernel<<<nblk(16*64*4096), 256, 0, stream>>>(ws + F_S2, ws + F_S3, ST + 4 * 128, b2g + 64, b2b + 64, 64,  1.f / 65536.f);
    bn_upadd_kernel<<<nblk(16*64*1024), 256, 0, stream>>>(ws + F_U1, ws + F_U2, ST + 2 * 128, b3g,      b3b,      32,  1.f / 16384.f);
    bn_upadd_kernel<<<nblk(16*64*16384), 256, 0, stream>>>(ws + F_S1, ws + F_S2, ST + 5 * 128, b3g + 64, b3b + 64, 128, 1.f / 262144.f);

    // ---- 3x3 convs (pre-BN) ----
    conv3x3_kernel<<<dim3(1, 16), 256, 0, stream>>>(ws + F_U3, cuw + 0 * 64 * 64 * 9, cub + 0,   ws + C_0, 8, 1);
    conv3x3_kernel<<<dim3(1, 16), 256, 0, stream>>>(ws + F_U2, cuw + 1 * 64 * 64 * 9, cub + 64,  ws + C_1, 16, 1);
    conv3x3_kernel<<<dim3(4, 16), 256, 0, stream>>>(ws + F_U1, cuw + 2 * 64 * 64 * 9, cub + 128, ws + C_2, 32, 2);
    conv3x3_kernel<<<dim3(64, 16), 256, 0, stream>>>(ws + F_S1, cuw + 3 * 64 * 64 * 9, cub + 192, ws + C_3, 128, 8);

    bn_stats_kernel<<<dim3(64, 16), 256, 0, stream>>>(ws + C_0, ST + 768 + 0 * 128, 36);
    bn_stats_kernel<<<dim3(64, 16), 256, 0, stream>>>(ws + C_1, ST + 768 + 1 * 128, 196);
    bn_stats_kernel<<<dim3(64, 16), 256, 0, stream>>>(ws + C_2, ST + 768 + 2 * 128, 900);
    bn_stats_kernel<<<dim3(64, 16), 256, 0, stream>>>(ws + C_3, ST + 768 + 3 * 128, 15876);

    bn_apply_kernel<<<nblk(16*64*36), 256, 0, stream>>>(ws + C_0, ST + 768 + 0 * 128, bug,       bub,       36,    1.f / 576.f);
    bn_apply_kernel<<<nblk(16*64*196), 256, 0, stream>>>(ws + C_1, ST + 768 + 1 * 128, bug + 64,  bub + 64,  196,   1.f / 3136.f);
    bn_apply_kernel<<<nblk(16*64*900), 256, 0, stream>>>(ws + C_2, ST + 768 + 2 * 128, bug + 128, bub + 128, 900,   1.f / 14400.f);
    bn_apply_kernel<<<nblk(16*64*15876), 256, 0, stream>>>(ws + C_3, ST + 768 + 3 * 128, bug + 192, bub + 192, 15876, 1.f / 254016.f);

    // ---- correlations v3 (atomicAdd into zeroed A buffers; ci split over z) ----
    corr3_kernel<6, 4> <<<dim3(8, 16, 4), 256, 0, stream>>>(ws + C_0, ws + C_3, ws + A_1);
    corr3_kernel<14, 8><<<dim3(8, 16, 8), 256, 0, stream>>>(ws + C_1, ws + C_3, ws + A_2);
    corr3_kernel<30, 8><<<dim3(8, 16, 8), 256, 0, stream>>>(ws + C_2, ws + C_3, ws + A_3);

    scalar_stats_kernel<<<512, 256, 0, stream>>>(ws + A_1, ST + 1280 + 0, 258064);
    scalar_stats_kernel<<<512, 256, 0, stream>>>(ws + A_2, ST + 1280 + 2, 258064);
    scalar_stats_kernel<<<512, 256, 0, stream>>>(ws + A_3, ST + 1280 + 4, 258064);

    final_kernel<<<1024, 256, 0, stream>>>(ws + A_1, ws + A_2, ws + A_3,
                                           ST + 1280, corr_g, corr_b, fusion_w, out);
}

// Round 4
// 2555.036 us; speedup vs baseline: 1.3283x; 1.1385x over previous
//
#include <hip/hip_runtime.h>

#define EPS 1e-5f

typedef __bf16 bf16x8 __attribute__((ext_vector_type(8)));
typedef float f32x4 __attribute__((ext_vector_type(4)));

// ---------------- workspace layout (float offsets) ----------------
constexpr size_t F_U3 = 0;                               // (16,64, 8, 8)
constexpr size_t F_U2 = F_U3 + (size_t)16*64*64;         // (16,64,16,16)
constexpr size_t F_U1 = F_U2 + (size_t)16*64*256;        // (16,64,32,32)
constexpr size_t F_S3 = F_U1 + (size_t)16*64*1024;       // (16,64,32,32)
constexpr size_t F_S2 = F_S3 + (size_t)16*64*1024;       // (16,64,64,64)
constexpr size_t F_S1 = F_S2 + (size_t)16*64*4096;       // (16,64,128,128)
constexpr size_t C_0  = F_S1 + (size_t)16*64*16384;      // (16,64,  6,  6)
constexpr size_t C_1  = C_0  + (size_t)16*64*36;         // (16,64, 14, 14)
constexpr size_t C_2  = C_1  + (size_t)16*64*196;        // (16,64, 30, 30)
constexpr size_t C_3  = C_2  + (size_t)16*64*900;        // (16,64,126,126)
constexpr size_t A_1  = C_3  + (size_t)16*64*15876;      // (16,127,127)
constexpr size_t A_2  = A_1  + (size_t)16*127*127;
constexpr size_t A_3  = A_2  + (size_t)16*127*127;
constexpr size_t STATS = A_3 + (size_t)16*127*127;       // 2048 floats
constexpr size_t WS_FLOATS = STATS + 2048;

// Correlation-GEMM scratch REUSES the dead F_* region (dead after conv3x3):
// C3T: bf16 [16][126][160][64] = 20,643,840 ushort = 10,321,920 float-slots
constexpr size_t C3T_OFF  = 0;
// Rp: fp32 [16][126][MT*16<=32][128] = 8,257,536 floats (reused per query)
constexpr size_t RP_OFF   = 10321920;
// packed A fragments (bf16), per query
constexpr size_t A3PK_OFF = RP_OFF + 8257536;            // 983,040 ushort
constexpr size_t A2PK_OFF = A3PK_OFF + 491520;           // 229,376 ushort
constexpr size_t A1PK_OFF = A2PK_OFF + 114688;           // 98,304 ushort
// ends at 19,234,816 < C_0 = 23,396,352  ✓

__device__ __forceinline__ unsigned short f2bf(float f)
{
    unsigned int x = __float_as_uint(f);
    unsigned int r = (x + 0x7FFFu + ((x >> 16) & 1u)) >> 16;
    return (unsigned short)r;
}

// ---------------- 1x1 conv + bias (pre-BN) ----------------
template<int CIN>
__global__ __launch_bounds__(256) void conv1x1_kernel(
    const float* __restrict__ in, const float* __restrict__ w,
    const float* __restrict__ bias, float* __restrict__ out, int HW)
{
    __shared__ __align__(16) float wl[64][64];   // [ci][co] chunk
    const int n = blockIdx.y;
    const int p = blockIdx.x * 256 + threadIdx.x;
    const bool act = (p < HW);
    float4 acc[16];
    #pragma unroll
    for (int i = 0; i < 16; ++i) acc[i] = make_float4(0.f, 0.f, 0.f, 0.f);
    const float* inp = in + (size_t)n * CIN * HW + p;
    for (int cb = 0; cb < CIN; cb += 64) {
        __syncthreads();
        #pragma unroll
        for (int t = 0; t < 16; ++t) {
            int e = threadIdx.x + t * 256;
            int ci = e >> 6, co = e & 63;
            wl[ci][co] = w[(size_t)co * CIN + cb + ci];
        }
        __syncthreads();
        if (act) {
            #pragma unroll 4
            for (int ci = 0; ci < 64; ++ci) {
                float x = inp[(size_t)(cb + ci) * HW];
                const float4* wp = (const float4*)(&wl[ci][0]);
                #pragma unroll
                for (int j = 0; j < 16; ++j) {
                    float4 wv = wp[j];
                    acc[j].x += wv.x * x; acc[j].y += wv.y * x;
                    acc[j].z += wv.z * x; acc[j].w += wv.w * x;
                }
            }
        }
    }
    if (act) {
        float* op = out + (size_t)n * 64 * HW + p;
        #pragma unroll
        for (int j = 0; j < 16; ++j) {
            op[(size_t)(4*j+0)*HW] = acc[j].x + bias[4*j+0];
            op[(size_t)(4*j+1)*HW] = acc[j].y + bias[4*j+1];
            op[(size_t)(4*j+2)*HW] = acc[j].z + bias[4*j+2];
            op[(size_t)(4*j+3)*HW] = acc[j].w + bias[4*j+3];
        }
    }
}

// ---------------- block reduce (sum, sumsq), blockDim.x == 256 ----------------
__device__ __forceinline__ void block_red2(float& s, float& s2)
{
    #pragma unroll
    for (int off = 32; off > 0; off >>= 1) {
        s  += __shfl_down(s,  off);
        s2 += __shfl_down(s2, off);
    }
    __shared__ float r[16];
    int wv = threadIdx.x >> 6;
    if ((threadIdx.x & 63) == 0) { r[wv] = s; r[8 + wv] = s2; }
    __syncthreads();
    if (threadIdx.x == 0) {
        s  = r[0] + r[1] + r[2] + r[3];
        s2 = r[8] + r[9] + r[10] + r[11];
    }
}

__global__ __launch_bounds__(256) void bn_stats_kernel(
    const float* __restrict__ x, float* __restrict__ st, int HW)
{
    const int c = blockIdx.x, n = blockIdx.y;
    const float* xc = x + ((size_t)n * 64 + c) * HW;
    float s = 0.f, s2 = 0.f;
    for (int p = threadIdx.x; p < HW; p += 256) { float v = xc[p]; s += v; s2 += v * v; }
    block_red2(s, s2);
    if (threadIdx.x == 0) { atomicAdd(&st[c], s); atomicAdd(&st[64 + c], s2); }
}

__global__ __launch_bounds__(256) void bn_apply_kernel(
    float* __restrict__ x, const float* __restrict__ st,
    const float* __restrict__ g, const float* __restrict__ b,
    int HW, float invCnt)
{
    const int total = 16 * 64 * HW;
    for (int idx = blockIdx.x * 256 + threadIdx.x; idx < total; idx += gridDim.x * 256) {
        int c = (idx / HW) & 63;
        float m = st[c] * invCnt;
        float v = st[64 + c] * invCnt - m * m;
        float inv = 1.0f / sqrtf(v + EPS);
        x[idx] = g[c] * (x[idx] - m) * inv + b[c];
    }
}

__global__ __launch_bounds__(256) void bn_upadd_kernel(
    float* __restrict__ x2, const float* __restrict__ u1,
    const float* __restrict__ st, const float* __restrict__ g,
    const float* __restrict__ b, int H2, float invCnt)
{
    const int W2 = H2, H1 = H2 >> 1, W1 = H1;
    const int total = 16 * 64 * H2 * W2;
    for (int idx = blockIdx.x * 256 + threadIdx.x; idx < total; idx += gridDim.x * 256) {
        int xx = idx % W2;
        int t = idx / W2;
        int yy = t % H2; t /= H2;
        int c = t & 63, n = t >> 6;
        float m = st[c] * invCnt;
        float v = st[64 + c] * invCnt - m * m;
        float val = g[c] * (x2[idx] - m) / sqrtf(v + EPS) + b[c];
        float hy = fminf(fmaxf(yy * 0.5f - 0.25f, 0.f), (float)(H1 - 1));
        float wx = fminf(fmaxf(xx * 0.5f - 0.25f, 0.f), (float)(W1 - 1));
        int h0 = (int)hy, w0 = (int)wx;
        int h1 = (h0 + 1 < H1) ? h0 + 1 : H1 - 1;
        int w1 = (w0 + 1 < W1) ? w0 + 1 : W1 - 1;
        float th = hy - h0, tw = wx - w0;
        const float* up = u1 + ((size_t)n * 64 + c) * H1 * W1;
        float v00 = up[h0 * W1 + w0], v01 = up[h0 * W1 + w1];
        float v10 = up[h1 * W1 + w0], v11 = up[h1 * W1 + w1];
        float bi = (v00 * (1.f - tw) + v01 * tw) * (1.f - th)
                 + (v10 * (1.f - tw) + v11 * tw) * th;
        x2[idx] = val + bi;
    }
}

// ---------------- 3x3 VALID conv + bias (pre-BN), 64->64 ch ----------------
__global__ __launch_bounds__(256) void conv3x3_kernel(
    const float* __restrict__ in, const float* __restrict__ w,
    const float* __restrict__ bias, float* __restrict__ out,
    int H, int tilesX)
{
    const int W = H, OH = H - 2, OW = W - 2;
    __shared__ __align__(16) float xs[8][18][19];
    __shared__ __align__(16) float wsm[8][9][64];   // [ci][tap][co]
    const int n = blockIdx.y;
    const int ty0 = (blockIdx.x / tilesX) * 16, tx0 = (blockIdx.x % tilesX) * 16;
    const int lx = threadIdx.x & 15, ly = threadIdx.x >> 4;
    const int oy = ty0 + ly, ox = tx0 + lx;
    const bool act = (oy < OH) && (ox < OW);
    float4 acc[16];
    #pragma unroll
    for (int i = 0; i < 16; ++i) acc[i] = make_float4(0.f, 0.f, 0.f, 0.f);
    for (int cb = 0; cb < 64; cb += 8) {
        __syncthreads();
        for (int t = threadIdx.x; t < 8 * 18 * 18; t += 256) {
            int ci = t / 324, r = t % 324;
            int yy = r / 18, xx = r % 18;
            int gy = ty0 + yy, gx = tx0 + xx;
            float v = 0.f;
            if (gy < H && gx < W) v = in[(((size_t)n * 64 + cb + ci) * H + gy) * W + gx];
            xs[ci][yy][xx] = v;
        }
        for (int t = threadIdx.x; t < 8 * 9 * 64; t += 256) {
            int ci = t / 576, r = t % 576;
            int k = r >> 6, co = r & 63;
            wsm[ci][k][co] = w[(((size_t)co * 64) + cb + ci) * 9 + k];
        }
        __syncthreads();
        #pragma unroll
        for (int ci = 0; ci < 8; ++ci) {
            float xv[9];
            #pragma unroll
            for (int dy = 0; dy < 3; ++dy)
                #pragma unroll
                for (int dx = 0; dx < 3; ++dx)
                    xv[dy * 3 + dx] = xs[ci][ly + dy][lx + dx];
            #pragma unroll
            for (int k = 0; k < 9; ++k) {
                const float4* wp = (const float4*)(&wsm[ci][k][0]);
                float xk = xv[k];
                #pragma unroll
                for (int j = 0; j < 16; ++j) {
                    float4 wv = wp[j];
                    acc[j].x += wv.x * xk; acc[j].y += wv.y * xk;
                    acc[j].z += wv.z * xk; acc[j].w += wv.w * xk;
                }
            }
        }
    }
    if (act) {
        #pragma unroll
        for (int j = 0; j < 16; ++j) {
            out[(((size_t)n * 64 + 4*j+0) * OH + oy) * OW + ox] = acc[j].x + bias[4*j+0];
            out[(((size_t)n * 64 + 4*j+1) * OH + oy) * OW + ox] = acc[j].y + bias[4*j+1];
            out[(((size_t)n * 64 + 4*j+2) * OH + oy) * OW + ox] = acc[j].z + bias[4*j+2];
            out[(((size_t)n * 64 + 4*j+3) * OH + oy) * OW + ox] = acc[j].w + bias[4*j+3];
        }
    }
}

// ---------------- correlation as MFMA GEMM ----------------
// R'[b][z][ky][x] = sum_{kx,ci} q[b][ci][ky][kx] * s[b][ci][z][x+kx-PAD]
// out[b][y][x]    = sum_ky R'[b][y+ky-PAD][ky][x]
// C3T: bf16 [b][z][w][ci], w = col + 15 (frame pad 15 serves PAD=15/7/3 via WOFF)

// C_3 (post-BN fp32) -> C3T bf16 transposed. grid (126 z, 16 b)
__global__ __launch_bounds__(256) void corr_transpose_kernel(
    const float* __restrict__ C3, unsigned short* __restrict__ C3T)
{
    __shared__ unsigned short tmp[126 * 65];
    const int z = blockIdx.x, b = blockIdx.y;
    for (int e = threadIdx.x; e < 64 * 126; e += 256) {
        int ci = e / 126, col = e % 126;
        float f = C3[(((size_t)b * 64 + ci) * 126 + z) * 126 + col];
        tmp[col * 65 + ci] = f2bf(f);
    }
    __syncthreads();
    unsigned short* dst = C3T + ((size_t)(b * 126 + z)) * 160 * 64;
    for (int e = threadIdx.x; e < 160 * 64; e += 256) {
        int w = e >> 6, ci = e & 63;
        unsigned short v = (w >= 15 && w < 141) ? tmp[(w - 15) * 65 + ci] : (unsigned short)0;
        dst[e] = v;
    }
}

// pack q (post-BN fp32) into A-fragment order: Apack[b][mt][s][lane][j]
// k-bijection: k=(g,j): ci=(s&1)*32+g*8+j, kx=s>>1; m-row: ky=mt*16+(l&15)
template<int QH, int MT, int NS>
__global__ __launch_bounds__(256) void corr_packA_kernel(
    const float* __restrict__ q, unsigned short* __restrict__ Apack)
{
    const int total = 16 * MT * NS * 64;
    int idx = blockIdx.x * 256 + threadIdx.x;
    if (idx >= total) return;
    int l = idx & 63;
    int s = (idx >> 6) % NS;
    int mt = ((idx >> 6) / NS) % MT;
    int b = idx / (64 * NS * MT);
    int ky = mt * 16 + (l & 15);
    int kx = s >> 1;
    int cib = (s & 1) * 32 + (l >> 4) * 8;
    unsigned int o[4];
    #pragma unroll
    for (int h = 0; h < 4; ++h) {
        unsigned int lo = 0, hi = 0;
        if (ky < QH) {
            int ci0 = cib + 2 * h;
            lo = f2bf(q[(((size_t)b * 64 + ci0) * QH + ky) * QH + kx]);
            hi = f2bf(q[(((size_t)b * 64 + ci0 + 1) * QH + ky) * QH + kx]);
        }
        o[h] = lo | (hi << 16);
    }
    uint4 v = make_uint4(o[0], o[1], o[2], o[3]);
    *(uint4*)(Apack + (size_t)idx * 8) = v;
}

// GEMM per (b,z): M=MT*16 (ky), N=128 (x, 8 tiles: 2 per wave), K=NS*32.
// Pure global loads (L2-resident) + MFMA; no LDS, no barriers.
template<int MT, int NS, int WOFF>
__global__ __launch_bounds__(256) void corr_mfma_kernel(
    const unsigned short* __restrict__ Apack,
    const unsigned short* __restrict__ C3T,
    float* __restrict__ Rp)
{
    const int z = blockIdx.x, b = blockIdx.y;
    const int l = threadIdx.x & 63, wv = threadIdx.x >> 6;
    const int lr = l & 15, lg = l >> 4;
    f32x4 acc[MT][2];
    #pragma unroll
    for (int mt = 0; mt < MT; ++mt)
        #pragma unroll
        for (int nt = 0; nt < 2; ++nt)
            acc[mt][nt] = (f32x4){0.f, 0.f, 0.f, 0.f};
    const unsigned short* arow = Apack + (size_t)b * MT * NS * 512 + (size_t)l * 8;
    const unsigned short* brow = C3T + ((size_t)(b * 126 + z)) * 160 * 64
                               + (size_t)(32 * wv + lr + WOFF) * 64 + lg * 8;
    #pragma unroll 2
    for (int s = 0; s < NS; ++s) {
        const unsigned short* bp = brow + (size_t)(s >> 1) * 64 + (s & 1) * 32;
        uint4 b0 = *(const uint4*)bp;
        uint4 b1 = *(const uint4*)(bp + 16 * 64);
        bf16x8 bf0 = __builtin_bit_cast(bf16x8, b0);
        bf16x8 bf1 = __builtin_bit_cast(bf16x8, b1);
        #pragma unroll
        for (int mt = 0; mt < MT; ++mt) {
            uint4 a = *(const uint4*)(arow + (size_t)(mt * NS + s) * 512);
            bf16x8 af = __builtin_bit_cast(bf16x8, a);
            acc[mt][0] = __builtin_amdgcn_mfma_f32_16x16x32_bf16(af, bf0, acc[mt][0], 0, 0, 0);
            acc[mt][1] = __builtin_amdgcn_mfma_f32_16x16x32_bf16(af, bf1, acc[mt][1], 0, 0, 0);
        }
    }
    float* rbase = Rp + ((size_t)(b * 126 + z)) * MT * 16 * 128;
    #pragma unroll
    for (int mt = 0; mt < MT; ++mt)
        #pragma unroll
        for (int nt = 0; nt < 2; ++nt) {
            int x = 32 * wv + nt * 16 + lr;
            #pragma unroll
            for (int r = 0; r < 4; ++r) {
                int ky = mt * 16 + lg * 4 + r;
                rbase[(size_t)ky * 128 + x] = acc[mt][nt][r];
            }
        }
}

// out[b][y][x] = sum_ky R'[b][y+ky-PAD][ky][x]; fused whole-tensor stats
template<int QH, int PAD, int MT>
__global__ __launch_bounds__(256) void corr_reduce_kernel(
    const float* __restrict__ Rp, float* __restrict__ outA,
    float* __restrict__ st)
{
    const int y = blockIdx.x, b = blockIdx.y;
    const int x = threadIdx.x;
    float v = 0.f;
    if (x < 127) {
        #pragma unroll
        for (int ky = 0; ky < QH; ++ky) {
            int z = y + ky - PAD;
            if (z >= 0 && z < 126)
                v += Rp[(((size_t)(b * 126 + z)) * MT * 16 + ky) * 128 + x];
        }
        outA[((size_t)b * 127 + y) * 127 + x] = v;
    }
    float s = v, s2 = v * v;
    block_red2(s, s2);
    if (threadIdx.x == 0) { atomicAdd(&st[0], s); atomicAdd(&st[1], s2); }
}

// normalize each A, softmax-weighted fuse, bilinear 127->128 (align_corners=True)
__global__ __launch_bounds__(256) void final_kernel(
    const float* __restrict__ A1p, const float* __restrict__ A2p,
    const float* __restrict__ A3p, const float* __restrict__ st,
    const float* __restrict__ cg, const float* __restrict__ cbv,
    const float* __restrict__ fwp, float* __restrict__ out)
{
    int idx = blockIdx.x * 256 + threadIdx.x;
    if (idx >= 16 * 128 * 128) return;
    int x = idx & 127, y = (idx >> 7) & 127, n = idx >> 14;
    float f0 = fwp[0], f1 = fwp[1], f2 = fwp[2];
    float mx = fmaxf(fmaxf(f0, f1), f2);
    float e0 = expf(f0 - mx), e1 = expf(f1 - mx), e2 = expf(f2 - mx);
    float inv = 1.f / (e0 + e1 + e2);
    float wgt[3] = { e0 * inv, e1 * inv, e2 * inv };
    const float invCnt = 1.f / 258064.f;
    float coef[3], K = 0.f;
    #pragma unroll
    for (int a = 0; a < 3; ++a) {
        float m = st[2 * a] * invCnt;
        float v = st[2 * a + 1] * invCnt - m * m;
        float sc = cg[a] / sqrtf(v + EPS);
        coef[a] = wgt[a] * sc;
        K += wgt[a] * (cbv[a] - sc * m);
    }
    float s = (float)(126.0 / 127.0);
    float hy = y * s, wx = x * s;
    int h0 = (int)hy, w0 = (int)wx;
    int h1 = (h0 + 1 < 127) ? h0 + 1 : 126;
    int w1 = (w0 + 1 < 127) ? w0 + 1 : 126;
    float th = hy - h0, tw = wx - w0;
    const float* As[3] = { A1p, A2p, A3p };
    float val = K;
    #pragma unroll
    for (int a = 0; a < 3; ++a) {
        const float* Ab = As[a] + (size_t)n * 127 * 127;
        float v00 = Ab[h0 * 127 + w0], v01 = Ab[h0 * 127 + w1];
        float v10 = Ab[h1 * 127 + w0], v11 = Ab[h1 * 127 + w1];
        val += coef[a] * ((v00 * (1.f - tw) + v01 * tw) * (1.f - th)
                        + (v10 * (1.f - tw) + v11 * tw) * th);
    }
    out[idx] = val;
}

static inline int nblk(long long total) {
    long long b = (total + 255) / 256;
    return (int)(b < 2048 ? b : 2048);
}

extern "C" void kernel_launch(void* const* d_in, const int* in_sizes, int n_in,
                              void* d_out, int out_size, void* d_ws, size_t ws_size,
                              hipStream_t stream)
{
    const float* sat1 = (const float*)d_in[0];
    const float* sat2 = (const float*)d_in[1];
    const float* sat3 = (const float*)d_in[2];
    const float* uav1 = (const float*)d_in[3];
    const float* uav2 = (const float*)d_in[4];
    const float* uav3 = (const float*)d_in[5];
    const float* c1w = (const float*)d_in[6];
    const float* c1b = (const float*)d_in[7];
    const float* b1g = (const float*)d_in[8];
    const float* b1b = (const float*)d_in[9];
    const float* c2w = (const float*)d_in[10];
    const float* c2b = (const float*)d_in[11];
    const float* b2g = (const float*)d_in[12];
    const float* b2b = (const float*)d_in[13];
    const float* c3w = (const float*)d_in[14];
    const float* c3b = (const float*)d_in[15];
    const float* b3g = (const float*)d_in[16];
    const float* b3b = (const float*)d_in[17];
    const float* cuw = (const float*)d_in[18];
    const float* cub = (const float*)d_in[19];
    const float* bug = (const float*)d_in[20];
    const float* bub = (const float*)d_in[21];
    const float* corr_g = (const float*)d_in[22];
    const float* corr_b = (const float*)d_in[23];
    const float* fusion_w = (const float*)d_in[24];
    float* ws = (float*)d_ws;
    float* out = (float*)d_out;
    float* ST = ws + STATS;

    // zero STATS (all atomics accumulate here)
    hipMemsetAsync(ST, 0, 2048 * sizeof(float), stream);

    // ---- 1x1 convs (pre-BN) ----
    conv1x1_kernel<512><<<dim3(1, 16), 256, 0, stream>>>(uav3, c1w,            c1b,      ws + F_U3, 64);
    conv1x1_kernel<256><<<dim3(1, 16), 256, 0, stream>>>(uav2, c2w,            c2b,      ws + F_U2, 256);
    conv1x1_kernel<128><<<dim3(4, 16), 256, 0, stream>>>(uav1, c3w,            c3b,      ws + F_U1, 1024);
    conv1x1_kernel<512><<<dim3(4, 16), 256, 0, stream>>>(sat3, c1w + 64 * 512, c1b + 64, ws + F_S3, 1024);
    conv1x1_kernel<256><<<dim3(16, 16), 256, 0, stream>>>(sat2, c2w + 64 * 256, c2b + 64, ws + F_S2, 4096);
    conv1x1_kernel<128><<<dim3(64, 16), 256, 0, stream>>>(sat1, c3w + 64 * 128, c3b + 64, ws + F_S1, 16384);

    // ---- BN stats (pre-BN tensors) ----
    bn_stats_kernel<<<dim3(64, 16), 256, 0, stream>>>(ws + F_U3, ST + 0 * 128, 64);
    bn_stats_kernel<<<dim3(64, 16), 256, 0, stream>>>(ws + F_U2, ST + 1 * 128, 256);
    bn_stats_kernel<<<dim3(64, 16), 256, 0, stream>>>(ws + F_U1, ST + 2 * 128, 1024);
    bn_stats_kernel<<<dim3(64, 16), 256, 0, stream>>>(ws + F_S3, ST + 3 * 128, 1024);
    bn_stats_kernel<<<dim3(64, 16), 256, 0, stream>>>(ws + F_S2, ST + 4 * 128, 4096);
    bn_stats_kernel<<<dim3(64, 16), 256, 0, stream>>>(ws + F_S1, ST + 5 * 128, 16384);

    // ---- top-down pyramid (BN in place; upsample-add fused) ----
    bn_apply_kernel<<<nblk(16*64*64), 256, 0, stream>>>(ws + F_U3, ST + 0 * 128, b1g,      b1b,      64,   1.f / 1024.f);
    bn_apply_kernel<<<nblk(16*64*1024), 256, 0, stream>>>(ws + F_S3, ST + 3 * 128, b1g + 64, b1b + 64, 1024, 1.f / 16384.f);
    bn_upadd_kernel<<<nblk(16*64*256), 256, 0, stream>>>(ws + F_U2, ws + F_U3, ST + 1 * 128, b2g,      b2b,      16,  1.f / 4096.f);
    bn_upadd_kernel<<<nblk(16*64*4096), 256, 0, stream>>>(ws + F_S2, ws + F_S3, ST + 4 * 128, b2g + 64, b2b + 64, 64,  1.f / 65536.f);
    bn_upadd_kernel<<<nblk(16*64*1024), 256, 0, stream>>>(ws + F_U1, ws + F_U2, ST + 2 * 128, b3g,      b3b,      32,  1.f / 16384.f);
    bn_upadd_kernel<<<nblk(16*64*16384), 256, 0, stream>>>(ws + F_S1, ws + F_S2, ST + 5 * 128, b3g + 64, b3b + 64, 128, 1.f / 262144.f);

    // ---- 3x3 convs (pre-BN) ----
    conv3x3_kernel<<<dim3(1, 16), 256, 0, stream>>>(ws + F_U3, cuw + 0 * 64 * 64 * 9, cub + 0,   ws + C_0, 8, 1);
    conv3x3_kernel<<<dim3(1, 16), 256, 0, stream>>>(ws + F_U2, cuw + 1 * 64 * 64 * 9, cub + 64,  ws + C_1, 16, 1);
    conv3x3_kernel<<<dim3(4, 16), 256, 0, stream>>>(ws + F_U1, cuw + 2 * 64 * 64 * 9, cub + 128, ws + C_2, 32, 2);
    conv3x3_kernel<<<dim3(64, 16), 256, 0, stream>>>(ws + F_S1, cuw + 3 * 64 * 64 * 9, cub + 192, ws + C_3, 128, 8);

    bn_stats_kernel<<<dim3(64, 16), 256, 0, stream>>>(ws + C_0, ST + 768 + 0 * 128, 36);
    bn_stats_kernel<<<dim3(64, 16), 256, 0, stream>>>(ws + C_1, ST + 768 + 1 * 128, 196);
    bn_stats_kernel<<<dim3(64, 16), 256, 0, stream>>>(ws + C_2, ST + 768 + 2 * 128, 900);
    bn_stats_kernel<<<dim3(64, 16), 256, 0, stream>>>(ws + C_3, ST + 768 + 3 * 128, 15876);

    bn_apply_kernel<<<nblk(16*64*36), 256, 0, stream>>>(ws + C_0, ST + 768 + 0 * 128, bug,       bub,       36,    1.f / 576.f);
    bn_apply_kernel<<<nblk(16*64*196), 256, 0, stream>>>(ws + C_1, ST + 768 + 1 * 128, bug + 64,  bub + 64,  196,   1.f / 3136.f);
    bn_apply_kernel<<<nblk(16*64*900), 256, 0, stream>>>(ws + C_2, ST + 768 + 2 * 128, bug + 128, bub + 128, 900,   1.f / 14400.f);
    bn_apply_kernel<<<nblk(16*64*15876), 256, 0, stream>>>(ws + C_3, ST + 768 + 3 * 128, bug + 192, bub + 192, 15876, 1.f / 254016.f);

    // ---- correlations via MFMA GEMM (F_* region is dead now; reuse it) ----
    unsigned short* C3T  = (unsigned short*)(ws + C3T_OFF);
    float*          RP   = ws + RP_OFF;
    unsigned short* A3PK = (unsigned short*)(ws + A3PK_OFF);
    unsigned short* A2PK = (unsigned short*)(ws + A2PK_OFF);
    unsigned short* A1PK = (unsigned short*)(ws + A1PK_OFF);

    corr_transpose_kernel<<<dim3(126, 16), 256, 0, stream>>>(ws + C_3, C3T);
    corr_packA_kernel<30, 2, 60><<<(16*2*60*64 + 255) / 256, 256, 0, stream>>>(ws + C_2, A3PK);
    corr_packA_kernel<14, 1, 28><<<(16*1*28*64 + 255) / 256, 256, 0, stream>>>(ws + C_1, A2PK);
    corr_packA_kernel< 6, 1, 12><<<(16*1*12*64 + 255) / 256, 256, 0, stream>>>(ws + C_0, A1PK);

    corr_mfma_kernel<2, 60, 0><<<dim3(126, 16), 256, 0, stream>>>(A3PK, C3T, RP);
    corr_reduce_kernel<30, 15, 2><<<dim3(127, 16), 256, 0, stream>>>(RP, ws + A_3, ST + 1280 + 4);
    corr_mfma_kernel<1, 28, 8><<<dim3(126, 16), 256, 0, stream>>>(A2PK, C3T, RP);
    corr_reduce_kernel<14, 7, 1><<<dim3(127, 16), 256, 0, stream>>>(RP, ws + A_2, ST + 1280 + 2);
    corr_mfma_kernel<1, 12, 12><<<dim3(126, 16), 256, 0, stream>>>(A1PK, C3T, RP);
    corr_reduce_kernel<6, 3, 1><<<dim3(127, 16), 256, 0, stream>>>(RP, ws + A_1, ST + 1280 + 0);

    final_kernel<<<1024, 256, 0, stream>>>(ws + A_1, ws + A_2, ws + A_3,
                                           ST + 1280, corr_g, corr_b, fusion_w, out);
}